// Round 2
// baseline (184.646 us; speedup 1.0000x reference)
//
#include <hip/hip_runtime.h>
#include <hip/hip_bf16.h>

#define BB 2
#define CC 64
#define HH 64
#define TT 512
#define FF 64
#define DD 32

// ---------------------------------------------------------------------------
// K1: Q = w_mic @ x_mic + b_mic ; K = w_ref @ x_ref + b_ref
// One block per (b, t, which). LDS: X tile [c][f] (broadcast-read as float4),
// W transposed [c][h] (per-lane stride-65, conflict-free).
// Thread: h = tid&63 (lane), f-block of 16 = (tid>>6)*16.
// ---------------------------------------------------------------------------
__global__ __launch_bounds__(256) void k_qk(
    const float* __restrict__ x_mic, const float* __restrict__ x_ref,
    const float* __restrict__ w_mic, const float* __restrict__ b_mic,
    const float* __restrict__ w_ref, const float* __restrict__ b_ref,
    float* __restrict__ Q, float* __restrict__ K)
{
    __shared__ float Xs[CC * FF];     // [c][f], read broadcast -> no pad needed
    __shared__ float Wt[CC * 65];     // [c][h], pad 65

    const int tid = threadIdx.x;
    const int bx  = blockIdx.x;
    const int b   = bx / TT, t = bx % TT;
    const int which = blockIdx.y;

    const float* xsrc = which ? x_ref : x_mic;
    const float* wsrc = which ? w_ref : w_mic;
    const float* bsrc = which ? b_ref : b_mic;
    float* out = which ? K : Q;

    // stage X[c][f] (coalesced float4 rows of 256B)
    {
        const float4* xg = reinterpret_cast<const float4*>(
            xsrc + (size_t)b * CC * TT * FF + (size_t)t * FF);
        float4* xs4 = reinterpret_cast<float4*>(Xs);
        #pragma unroll
        for (int idx = tid; idx < CC * 16; idx += 256) {
            int c = idx >> 4, f4 = idx & 15;
            xs4[idx] = xg[(size_t)c * (TT * FF / 4) + f4];
        }
    }
    // stage Wt[c][h] = W[h][c]
    #pragma unroll
    for (int idx = tid; idx < HH * CC; idx += 256) {
        int h = idx >> 6, c = idx & 63;
        Wt[c * 65 + h] = wsrc[idx];
    }
    __syncthreads();

    const int h   = tid & 63;
    const int fq0 = (tid >> 6) * 4;   // float4 base index (f = fq0*4)

    float bv = bsrc[h];
    float acc[16];
    #pragma unroll
    for (int j = 0; j < 16; ++j) acc[j] = bv;

    const float4* xs4 = reinterpret_cast<const float4*>(Xs);
    #pragma unroll 4
    for (int c = 0; c < CC; ++c) {
        float w = Wt[c * 65 + h];
        float4 a0 = xs4[c * 16 + fq0 + 0];
        float4 a1 = xs4[c * 16 + fq0 + 1];
        float4 a2 = xs4[c * 16 + fq0 + 2];
        float4 a3 = xs4[c * 16 + fq0 + 3];
        acc[0]  += w * a0.x; acc[1]  += w * a0.y; acc[2]  += w * a0.z; acc[3]  += w * a0.w;
        acc[4]  += w * a1.x; acc[5]  += w * a1.y; acc[6]  += w * a1.z; acc[7]  += w * a1.w;
        acc[8]  += w * a2.x; acc[9]  += w * a2.y; acc[10] += w * a2.z; acc[11] += w * a2.w;
        acc[12] += w * a3.x; acc[13] += w * a3.y; acc[14] += w * a3.z; acc[15] += w * a3.w;
    }

    float* orow = out + ((size_t)(b * HH + h) * TT + t) * FF + fq0 * 4;
    float4* o4 = reinterpret_cast<float4*>(orow);
    o4[0] = make_float4(acc[0],  acc[1],  acc[2],  acc[3]);
    o4[1] = make_float4(acc[4],  acc[5],  acc[6],  acc[7]);
    o4[2] = make_float4(acc[8],  acc[9],  acc[10], acc[11]);
    o4[3] = make_float4(acc[12], acc[13], acc[14], acc[15]);
}

// ---------------------------------------------------------------------------
// K2: V[b,t,h,d] = (1/8) * sum_f Q[b,h,t,f] * K[b,h,t+d-31,f]
// Block per (t-tile=64, h, b). LDS: Q tile [64][68], K tile [95][68].
// Thread: 2 t-rows (i = (tid&31)*2) x 4 d (d0 = (tid>>5)*4) -> 7 b128 reads
// per f-quad for 32 FMA.  V stored layout (B,T,H,D) for K3 locality.
// ---------------------------------------------------------------------------
__global__ __launch_bounds__(256) void k_scores(
    const float* __restrict__ Q, const float* __restrict__ K, float* __restrict__ V)
{
    __shared__ float Qs[64 * 68];
    __shared__ float Ks[95 * 68];

    const int tid = threadIdx.x;
    const int t0  = blockIdx.x * 64;
    const int h   = blockIdx.y, b = blockIdx.z;

    const size_t base = ((size_t)(b * HH + h) * TT) * FF;
    const float4* qg = reinterpret_cast<const float4*>(Q + base);
    const float4* kg = reinterpret_cast<const float4*>(K + base);
    float4* qs4 = reinterpret_cast<float4*>(Qs);
    float4* ks4 = reinterpret_cast<float4*>(Ks);

    #pragma unroll
    for (int idx = tid; idx < 64 * 16; idx += 256) {
        int r = idx >> 4, f4 = idx & 15;
        qs4[r * 17 + f4] = qg[(t0 + r) * 16 + f4];
    }
    #pragma unroll
    for (int idx = tid; idx < 95 * 16; idx += 256) {
        int r = idx >> 4, f4 = idx & 15;
        int tt = t0 - 31 + r;
        float4 v = make_float4(0.f, 0.f, 0.f, 0.f);
        if (tt >= 0) v = kg[tt * 16 + f4];
        ks4[r * 17 + f4] = v;
    }
    __syncthreads();

    const int i  = (tid & 31) * 2;
    const int d0 = (tid >> 5) * 4;

    float acc0[4] = {0.f, 0.f, 0.f, 0.f};
    float acc1[4] = {0.f, 0.f, 0.f, 0.f};

    #pragma unroll 2
    for (int fq = 0; fq < 16; ++fq) {
        float4 q0 = qs4[i * 17 + fq];
        float4 q1 = qs4[(i + 1) * 17 + fq];
        float4 k[5];
        #pragma unroll
        for (int r = 0; r < 5; ++r) k[r] = ks4[(i + d0 + r) * 17 + fq];
        #pragma unroll
        for (int dd = 0; dd < 4; ++dd) {
            acc0[dd] += q0.x * k[dd].x + q0.y * k[dd].y + q0.z * k[dd].z + q0.w * k[dd].w;
            acc1[dd] += q1.x * k[dd+1].x + q1.y * k[dd+1].y + q1.z * k[dd+1].z + q1.w * k[dd+1].w;
        }
    }

    float4* vout0 = reinterpret_cast<float4*>(
        V + ((size_t)(b * TT + t0 + i) * HH + h) * DD + d0);
    float4* vout1 = reinterpret_cast<float4*>(
        V + ((size_t)(b * TT + t0 + i + 1) * HH + h) * DD + d0);
    vout0[0] = make_float4(acc0[0]*0.125f, acc0[1]*0.125f, acc0[2]*0.125f, acc0[3]*0.125f);
    vout1[0] = make_float4(acc1[0]*0.125f, acc1[1]*0.125f, acc1[2]*0.125f, acc1[3]*0.125f);
}

// ---------------------------------------------------------------------------
// K3: Vc[b,t,d] = b_conv + sum_{h,i,j} V[b,t+i-4,h,d+j-1]*wc[h,i,j];
//     A[b,t,:] = softmax_d(Vc).  Block per (t,b). V window staged in LDS with
//     d padded by 1 on each side (zeros), then 8-partials-per-d + shuffle
//     softmax on lanes 0..31.
// ---------------------------------------------------------------------------
__global__ __launch_bounds__(256) void k_conv_softmax(
    const float* __restrict__ V, const float* __restrict__ wconv,
    const float* __restrict__ bconv, float* __restrict__ A)
{
    __shared__ float Vs[5 * 64 * 34];   // [i][h][dpad], dpad = d+1, slots 0 & 33 zero
    __shared__ float wcs[960];          // [h][i][j]
    __shared__ float parts[8 * 32];

    const int tid = threadIdx.x;
    const int t = blockIdx.x, b = blockIdx.y;

    #pragma unroll
    for (int idx = tid; idx < 960; idx += 256) wcs[idx] = wconv[idx];

    for (int idx = tid; idx < 5 * 64 * 34; idx += 256) {
        int i   = idx / (64 * 34);
        int rem = idx % (64 * 34);
        int hh  = rem / 34;
        int dp  = rem % 34;
        int tt  = t - 4 + i;
        int d   = dp - 1;
        float v = 0.f;
        if (tt >= 0 && d >= 0 && d < 32)
            v = V[((size_t)(b * TT + tt) * HH + hh) * DD + d];
        Vs[idx] = v;
    }
    __syncthreads();

    const int d  = tid & 31;
    const int hg = tid >> 5;            // [0,8)
    float s = 0.f;
    #pragma unroll
    for (int i = 0; i < 5; ++i) {
        #pragma unroll
        for (int hh = 0; hh < 8; ++hh) {
            int hidx = hg * 8 + hh;
            const float* vrow = &Vs[(i * 64 + hidx) * 34 + d];  // vrow[j] = V[.., d+j-1]
            const float* wr   = &wcs[hidx * 15 + i * 3];
            s += vrow[0] * wr[0] + vrow[1] * wr[1] + vrow[2] * wr[2];
        }
    }
    parts[hg * 32 + d] = s;
    __syncthreads();

    if (tid < 32) {
        float vc = bconv[0];
        #pragma unroll
        for (int g = 0; g < 8; ++g) vc += parts[g * 32 + tid];
        float m = vc;
        #pragma unroll
        for (int off = 16; off >= 1; off >>= 1) m = fmaxf(m, __shfl_xor(m, off));
        float e = __expf(vc - m);
        float ssum = e;
        #pragma unroll
        for (int off = 16; off >= 1; off >>= 1) ssum += __shfl_xor(ssum, off);
        A[((size_t)(b * TT) + t) * DD + tid] = e / ssum;
    }
}

// ---------------------------------------------------------------------------
// K4: aligned[b,c,t,f] = sum_d A[b,t,d] * x_ref[b,c,t+d-31,f]
// Block per (t-tile=32, c, b). LDS: x_ref window [63][68], A tile [32][33].
// Thread: one t-row (i = tid>>3), 8 f's (f0 = (tid&7)*8) -> A broadcast is
// 1 read per 8 FMA.
// ---------------------------------------------------------------------------
__global__ __launch_bounds__(256) void k_align(
    const float* __restrict__ x_ref, const float* __restrict__ A, float* __restrict__ out)
{
    __shared__ float Xs[63 * 68];
    __shared__ float As[32 * 33];

    const int tid = threadIdx.x;
    const int t0  = blockIdx.x * 32;
    const int c   = blockIdx.y, b = blockIdx.z;

    const float4* xg = reinterpret_cast<const float4*>(
        x_ref + ((size_t)(b * CC + c) * TT) * FF);
    float4* xs4 = reinterpret_cast<float4*>(Xs);
    #pragma unroll
    for (int idx = tid; idx < 63 * 16; idx += 256) {
        int r = idx >> 4, f4 = idx & 15;
        int tt = t0 - 31 + r;
        float4 v = make_float4(0.f, 0.f, 0.f, 0.f);
        if (tt >= 0) v = xg[tt * 16 + f4];
        xs4[r * 17 + f4] = v;
    }
    #pragma unroll
    for (int idx = tid; idx < 32 * 32; idx += 256) {
        int i = idx >> 5, d = idx & 31;
        As[i * 33 + d] = A[((size_t)(b * TT) + t0 + i) * DD + d];
    }
    __syncthreads();

    const int i   = tid >> 3;           // [0,32)
    const int fb4 = (tid & 7) * 2;      // float4 index base (f = fb4*4)

    float acc0x = 0.f, acc0y = 0.f, acc0z = 0.f, acc0w = 0.f;
    float acc1x = 0.f, acc1y = 0.f, acc1z = 0.f, acc1w = 0.f;

    #pragma unroll 4
    for (int d = 0; d < 32; ++d) {
        float a = As[i * 33 + d];
        float4 x0 = xs4[(i + d) * 17 + fb4];
        float4 x1 = xs4[(i + d) * 17 + fb4 + 1];
        acc0x += a * x0.x; acc0y += a * x0.y; acc0z += a * x0.z; acc0w += a * x0.w;
        acc1x += a * x1.x; acc1y += a * x1.y; acc1z += a * x1.z; acc1w += a * x1.w;
    }

    float* orow = out + ((size_t)(b * CC + c) * TT + t0 + i) * FF + fb4 * 4;
    float4* o4 = reinterpret_cast<float4*>(orow);
    o4[0] = make_float4(acc0x, acc0y, acc0z, acc0w);
    o4[1] = make_float4(acc1x, acc1y, acc1z, acc1w);
}

// ---------------------------------------------------------------------------
extern "C" void kernel_launch(void* const* d_in, const int* in_sizes, int n_in,
                              void* d_out, int out_size, void* d_ws, size_t ws_size,
                              hipStream_t stream)
{
    const float* x_mic  = (const float*)d_in[0];
    const float* x_ref  = (const float*)d_in[1];
    const float* w_mic  = (const float*)d_in[2];
    const float* b_mic  = (const float*)d_in[3];
    const float* w_ref  = (const float*)d_in[4];
    const float* b_ref  = (const float*)d_in[5];
    const float* w_conv = (const float*)d_in[6];
    const float* b_conv = (const float*)d_in[7];
    float* out = (float*)d_out;

    float* ws = (float*)d_ws;
    float* Q = ws;                       // B*H*T*F = 4194304 floats
    float* K = ws + 4194304;             // 4194304 floats
    float* V = ws + 8388608;             // B*T*H*D = 2097152 floats
    float* A = ws + 10485760;            // B*T*D   = 32768 floats

    k_qk<<<dim3(BB * TT, 2), 256, 0, stream>>>(x_mic, x_ref, w_mic, b_mic,
                                               w_ref, b_ref, Q, K);
    k_scores<<<dim3(TT / 64, HH, BB), 256, 0, stream>>>(Q, K, V);
    k_conv_softmax<<<dim3(TT, BB), 256, 0, stream>>>(V, w_conv, b_conv, A);
    k_align<<<dim3(TT / 32, CC, BB), 256, 0, stream>>>(x_ref, A, out);
}

// Round 3
// 161.427 us; speedup vs baseline: 1.1438x; 1.1438x over previous
//
#include <hip/hip_runtime.h>
#include <hip/hip_bf16.h>

#define BB 2
#define CC 64
#define HH 64
#define TT 512
#define FF 64
#define DD 32

// ---------------------------------------------------------------------------
// K1: Q = w_mic @ x_mic + b_mic ; K = w_ref @ x_ref + b_ref
// Block per (b,t,which). X tile [c][f] read as all-lane broadcasts (free).
// W stored [h][c] pad-68 (identity-copy staging), read b128 along c.
// Thread: h = tid&63, 16 f = (tid>>6)*16.
// ---------------------------------------------------------------------------
__global__ __launch_bounds__(256) void k_qk(
    const float* __restrict__ x_mic, const float* __restrict__ x_ref,
    const float* __restrict__ w_mic, const float* __restrict__ b_mic,
    const float* __restrict__ w_ref, const float* __restrict__ b_ref,
    float* __restrict__ Q, float* __restrict__ K)
{
    __shared__ float Xs[CC * FF];     // [c][f], broadcast-read
    __shared__ float Ws[HH * 68];     // [h][c], row pad 68 dw

    const int tid = threadIdx.x;
    const int b   = blockIdx.x / TT, t = blockIdx.x % TT;
    const int which = blockIdx.y;

    const float* xsrc = which ? x_ref : x_mic;
    const float* wsrc = which ? w_ref : w_mic;
    const float* bsrc = which ? b_ref : b_mic;
    float* out = which ? K : Q;

    {
        const float4* xg = reinterpret_cast<const float4*>(
            xsrc + (size_t)b * CC * TT * FF + (size_t)t * FF);
        float4* xs4 = reinterpret_cast<float4*>(Xs);
        #pragma unroll
        for (int idx = tid; idx < CC * 16; idx += 256) {
            int c = idx >> 4, f4 = idx & 15;
            xs4[idx] = xg[(size_t)c * (TT * FF / 4) + f4];
        }
    }
    {
        const float4* wg = reinterpret_cast<const float4*>(wsrc);
        float4* ws4 = reinterpret_cast<float4*>(Ws);
        #pragma unroll
        for (int idx = tid; idx < HH * 16; idx += 256) {
            int h = idx >> 4, c4 = idx & 15;
            ws4[h * 17 + c4] = wg[idx];      // identity copy, pad 68
        }
    }
    __syncthreads();

    const int h   = tid & 63;
    const int fq0 = (tid >> 6) * 4;

    float bv = bsrc[h];
    float acc[16];
    #pragma unroll
    for (int j = 0; j < 16; ++j) acc[j] = bv;

    const float4* xs4 = reinterpret_cast<const float4*>(Xs);
    const float4* ws4 = reinterpret_cast<const float4*>(Ws);
    #pragma unroll 4
    for (int c4 = 0; c4 < 16; ++c4) {
        float4 w4 = ws4[h * 17 + c4];
        #pragma unroll
        for (int j = 0; j < 4; ++j) {
            int c = c4 * 4 + j;
            float w = (j == 0) ? w4.x : (j == 1) ? w4.y : (j == 2) ? w4.z : w4.w;
            float4 a0 = xs4[c * 16 + fq0 + 0];
            float4 a1 = xs4[c * 16 + fq0 + 1];
            float4 a2 = xs4[c * 16 + fq0 + 2];
            float4 a3 = xs4[c * 16 + fq0 + 3];
            acc[0]  += w * a0.x; acc[1]  += w * a0.y; acc[2]  += w * a0.z; acc[3]  += w * a0.w;
            acc[4]  += w * a1.x; acc[5]  += w * a1.y; acc[6]  += w * a1.z; acc[7]  += w * a1.w;
            acc[8]  += w * a2.x; acc[9]  += w * a2.y; acc[10] += w * a2.z; acc[11] += w * a2.w;
            acc[12] += w * a3.x; acc[13] += w * a3.y; acc[14] += w * a3.z; acc[15] += w * a3.w;
        }
    }

    float4* o4 = reinterpret_cast<float4*>(
        out + ((size_t)(b * HH + h) * TT + t) * FF + fq0 * 4);
    o4[0] = make_float4(acc[0],  acc[1],  acc[2],  acc[3]);
    o4[1] = make_float4(acc[4],  acc[5],  acc[6],  acc[7]);
    o4[2] = make_float4(acc[8],  acc[9],  acc[10], acc[11]);
    o4[3] = make_float4(acc[12], acc[13], acc[14], acc[15]);
}

// ---------------------------------------------------------------------------
// K2: V[b,t,h,d] = (1/8) * sum_f Q[b,h,t,f] * K[b,h,t+d-31,f]
// Block per (t-tile=64, h, b). Q/K tiles XOR-swizzled: f4' = f4 ^ (row&7)
// -> conflict-free b128 reads (quarter-wave covers all 8 bank groups).
// Thread: t = (tid&31)|((tid>>7)<<5)  (1 row), d-block of 8 = ((tid>>5)&3)*8.
// ---------------------------------------------------------------------------
__global__ __launch_bounds__(256) void k_scores(
    const float* __restrict__ Q, const float* __restrict__ K, float* __restrict__ V)
{
    __shared__ float Qs[64 * 64];     // [row][f4^swz], no pad (XOR replaces it)
    __shared__ float Ks[95 * 64];

    const int tid = threadIdx.x;
    const int t0  = blockIdx.x * 64;
    const int h   = blockIdx.y, b = blockIdx.z;

    const size_t base = ((size_t)(b * HH + h) * TT) * FF;
    const float4* qg = reinterpret_cast<const float4*>(Q + base);
    const float4* kg = reinterpret_cast<const float4*>(K + base);
    float4* qs4 = reinterpret_cast<float4*>(Qs);
    float4* ks4 = reinterpret_cast<float4*>(Ks);

    #pragma unroll
    for (int idx = tid; idx < 64 * 16; idx += 256) {
        int r = idx >> 4, f4 = idx & 15;
        qs4[r * 16 + (f4 ^ (r & 7))] = qg[(t0 + r) * 16 + f4];
    }
    #pragma unroll
    for (int idx = tid; idx < 95 * 16; idx += 256) {
        int r = idx >> 4, f4 = idx & 15;
        int tt = t0 - 31 + r;
        float4 v = make_float4(0.f, 0.f, 0.f, 0.f);
        if (tt >= 0) v = kg[tt * 16 + f4];
        ks4[r * 16 + (f4 ^ (r & 7))] = v;
    }
    __syncthreads();

    const int tl = (tid & 31) | ((tid >> 7) << 5);   // 0..63
    const int d0 = ((tid >> 5) & 3) * 8;
    const int tb = tl + d0;                           // first k-row

    float acc[8];
    #pragma unroll
    for (int j = 0; j < 8; ++j) acc[j] = 0.f;

    #pragma unroll 4
    for (int fq = 0; fq < 16; ++fq) {
        float4 q = qs4[tl * 16 + (fq ^ (tl & 7))];
        #pragma unroll
        for (int dd = 0; dd < 8; ++dd) {
            int kr = tb + dd;
            float4 k = ks4[kr * 16 + (fq ^ (kr & 7))];
            acc[dd] += q.x * k.x + q.y * k.y + q.z * k.z + q.w * k.w;
        }
    }

    float4* v4 = reinterpret_cast<float4*>(
        V + ((size_t)(b * TT + t0 + tl) * HH + h) * DD + d0);
    v4[0] = make_float4(acc[0]*0.125f, acc[1]*0.125f, acc[2]*0.125f, acc[3]*0.125f);
    v4[1] = make_float4(acc[4]*0.125f, acc[5]*0.125f, acc[6]*0.125f, acc[7]*0.125f);
}

// ---------------------------------------------------------------------------
// K3: Vc[b,t,d] = b_conv + sum_{h,i,j} V[b,t+i-4,h,d+j-1]*wc[h,i,j];
//     A[b,t,:] = softmax_d(Vc).  Block per (t,b). V rows (2048 floats each)
//     staged via coalesced float4 at +4-float guard offset; d edges handled
//     by select-after-load (loads stay in-bounds via guard band).
// ---------------------------------------------------------------------------
__global__ __launch_bounds__(256) void k_conv_softmax(
    const float* __restrict__ V, const float* __restrict__ wconv,
    const float* __restrict__ bconv, float* __restrict__ A)
{
    __shared__ float Vs[4 + 5 * 2048 + 4];   // guard + data + guard
    __shared__ float wcs[960];               // [h][i][j]
    __shared__ float parts[8 * 32];

    const int tid = threadIdx.x;
    const int t = blockIdx.x, b = blockIdx.y;

    #pragma unroll
    for (int idx = tid; idx < 960; idx += 256) wcs[idx] = wconv[idx];

    const float4* vg = reinterpret_cast<const float4*>(V);
    float4* vs4 = reinterpret_cast<float4*>(Vs);
    #pragma unroll
    for (int idx = tid; idx < 5 * 512; idx += 256) {     // 512 float4 per row
        int i = idx >> 9, f4i = idx & 511;
        int tt = t - 4 + i;
        float4 v = make_float4(0.f, 0.f, 0.f, 0.f);
        if (tt >= 0) v = vg[((size_t)(b * TT) + tt) * 512 + f4i];
        vs4[1 + idx] = v;                                // +4-float guard
    }
    __syncthreads();

    const int d  = tid & 31;
    const int hg = tid >> 5;            // [0,8)
    float s = 0.f;
    #pragma unroll
    for (int i = 0; i < 5; ++i) {
        #pragma unroll
        for (int hh = 0; hh < 8; ++hh) {
            int h = hg * 8 + hh;
            int base = 4 + i * 2048 + h * 32 + d;
            float vm = Vs[base - 1];  vm = (d > 0)  ? vm : 0.f;
            float v0 = Vs[base];
            float vp = Vs[base + 1];  vp = (d < 31) ? vp : 0.f;
            const float* wr = &wcs[h * 15 + i * 3];
            s += vm * wr[0] + v0 * wr[1] + vp * wr[2];
        }
    }
    parts[hg * 32 + d] = s;
    __syncthreads();

    if (tid < 32) {
        float vc = bconv[0];
        #pragma unroll
        for (int g = 0; g < 8; ++g) vc += parts[g * 32 + tid];
        float m = vc;
        #pragma unroll
        for (int off = 16; off >= 1; off >>= 1) m = fmaxf(m, __shfl_xor(m, off));
        float e = __expf(vc - m);
        float ssum = e;
        #pragma unroll
        for (int off = 16; off >= 1; off >>= 1) ssum += __shfl_xor(ssum, off);
        A[((size_t)(b * TT) + t) * DD + tid] = e / ssum;
    }
}

// ---------------------------------------------------------------------------
// K4: aligned[b,c,t,f] = sum_d A[b,t,d] * x_ref[b,c,t+d-31,f]
// Block per (t-tile=32, c, b). Thread: f4 = tid&15 (quarter-wave spans all
// bank groups -> conflict-free), t-row = tid>>4, 2 passes of 16 rows.
// ---------------------------------------------------------------------------
__global__ __launch_bounds__(256) void k_align(
    const float* __restrict__ x_ref, const float* __restrict__ A, float* __restrict__ out)
{
    __shared__ float Xs[63 * 68];       // [row][f], pad 68 dw
    __shared__ float As[32 * 33];

    const int tid = threadIdx.x;
    const int t0  = blockIdx.x * 32;
    const int c   = blockIdx.y, b = blockIdx.z;

    const float4* xg = reinterpret_cast<const float4*>(
        x_ref + ((size_t)(b * CC + c) * TT) * FF);
    float4* xs4 = reinterpret_cast<float4*>(Xs);
    #pragma unroll
    for (int idx = tid; idx < 63 * 16; idx += 256) {
        int r = idx >> 4, f4 = idx & 15;
        int tt = t0 - 31 + r;
        float4 v = make_float4(0.f, 0.f, 0.f, 0.f);
        if (tt >= 0) v = xg[tt * 16 + f4];
        xs4[r * 17 + f4] = v;
    }
    #pragma unroll
    for (int idx = tid; idx < 32 * 32; idx += 256) {
        int i = idx >> 5, d = idx & 31;
        As[i * 33 + d] = A[((size_t)(b * TT) + t0 + i) * DD + d];
    }
    __syncthreads();

    const int f4 = tid & 15;
    const int i0 = tid >> 4;            // [0,16)
    float4* out4 = reinterpret_cast<float4*>(out);

    #pragma unroll
    for (int pass = 0; pass < 2; ++pass) {
        const int i = i0 + pass * 16;
        float ax = 0.f, ay = 0.f, az = 0.f, aw = 0.f;
        #pragma unroll 8
        for (int d = 0; d < 32; ++d) {
            float a = As[i * 33 + d];
            float4 x = xs4[(i + d) * 17 + f4];
            ax += a * x.x; ay += a * x.y; az += a * x.z; aw += a * x.w;
        }
        out4[((size_t)(b * CC + c) * TT + t0 + i) * 16 + f4] =
            make_float4(ax, ay, az, aw);
    }
}

// ---------------------------------------------------------------------------
extern "C" void kernel_launch(void* const* d_in, const int* in_sizes, int n_in,
                              void* d_out, int out_size, void* d_ws, size_t ws_size,
                              hipStream_t stream)
{
    const float* x_mic  = (const float*)d_in[0];
    const float* x_ref  = (const float*)d_in[1];
    const float* w_mic  = (const float*)d_in[2];
    const float* b_mic  = (const float*)d_in[3];
    const float* w_ref  = (const float*)d_in[4];
    const float* b_ref  = (const float*)d_in[5];
    const float* w_conv = (const float*)d_in[6];
    const float* b_conv = (const float*)d_in[7];
    float* out = (float*)d_out;

    float* ws = (float*)d_ws;
    float* Q = ws;                       // B*H*T*F = 4194304 floats
    float* K = ws + 4194304;             // 4194304 floats
    float* V = ws + 8388608;             // B*T*H*D = 2097152 floats
    float* A = ws + 10485760;            // B*T*D   = 32768 floats

    k_qk<<<dim3(BB * TT, 2), 256, 0, stream>>>(x_mic, x_ref, w_mic, b_mic,
                                               w_ref, b_ref, Q, K);
    k_scores<<<dim3(TT / 64, HH, BB), 256, 0, stream>>>(Q, K, V);
    k_conv_softmax<<<dim3(TT, BB), 256, 0, stream>>>(V, w_conv, b_conv, A);
    k_align<<<dim3(TT / 32, CC, BB), 256, 0, stream>>>(x_ref, A, out);
}

// Round 4
// 131.782 us; speedup vs baseline: 1.4012x; 1.2250x over previous
//
#include <hip/hip_runtime.h>
#include <hip/hip_bf16.h>

#define BB 2
#define CC 64
#define HH 64
#define TT 512
#define FF 64
#define DD 32

typedef short short8 __attribute__((ext_vector_type(8)));
typedef float f32x4  __attribute__((ext_vector_type(4)));

__device__ __forceinline__ unsigned short f2bf(float x) {
    union { float f; unsigned u; } v; v.f = x;
    unsigned r = v.u + 0x7FFFu + ((v.u >> 16) & 1u);   // RNE
    return (unsigned short)(r >> 16);
}

// ---------------------------------------------------------------------------
// K1 (MFMA): Qb = bf16(w_mic @ x_mic + b_mic); Kb likewise.  C[h][f] per t.
// A = W[h][c] bf16 LDS pitch-72; B^T = xT[f][c] bf16 pitch-72 built via
// in-register 4x4 quad-shuffle transpose (lanes l, l^16, l^32, l^48).
// Block: (b, t-pair) x which; 4 waves = 4 h-tiles (m-tiles).
// ---------------------------------------------------------------------------
__global__ __launch_bounds__(256) void k_qk(
    const float* __restrict__ x_mic, const float* __restrict__ x_ref,
    const float* __restrict__ w_mic, const float* __restrict__ b_mic,
    const float* __restrict__ w_ref, const float* __restrict__ b_ref,
    unsigned short* __restrict__ Qb, unsigned short* __restrict__ Kb)
{
    __shared__ unsigned short Wl[64 * 72];       // [h][c] pitch 72
    __shared__ unsigned short Xt[2][64 * 72];    // [t][f][c] pitch 72
    __shared__ float Bs[64];

    const int tid = threadIdx.x;
    const int b   = blockIdx.x >> 8;
    const int t0  = (blockIdx.x & 255) * 2;
    const int which = blockIdx.y;

    const float* xsrc = which ? x_ref : x_mic;
    const float* wsrc = which ? w_ref : w_mic;
    const float* bsrc = which ? b_ref : b_mic;
    unsigned short* outb = which ? Kb : Qb;

    const int l  = tid & 63;
    const int w  = tid >> 6;
    const int q  = l >> 4;        // quad index 0..3
    const int f4i = l & 15;       // float4 index along f (staging) / n-lane

    // ---- stage W as bf16 [h][c] pitch 72 (b64 writes along c) ----
    {
        const float4* wg = reinterpret_cast<const float4*>(wsrc);
        const int h  = tid >> 2;
        #pragma unroll
        for (int p = 0; p < 4; ++p) {
            const int c0 = (tid & 3) * 4 + p * 16;
            float4 wv = wg[h * 16 + (c0 >> 2)];
            unsigned w0 = (unsigned)f2bf(wv.x) | ((unsigned)f2bf(wv.y) << 16);
            unsigned w1 = (unsigned)f2bf(wv.z) | ((unsigned)f2bf(wv.w) << 16);
            uint2* dst = reinterpret_cast<uint2*>(&Wl[h * 72 + c0]);
            *dst = make_uint2(w0, w1);
        }
    }
    if (tid < 64) Bs[tid] = bsrc[tid];

    // ---- stage x transposed: xT[f][c] bf16, quad-shuffle 4x4 transpose ----
    {
        const float4* xg = reinterpret_cast<const float4*>(
            xsrc + (size_t)b * CC * TT * FF);
        #pragma unroll
        for (int t = 0; t < 2; ++t) {
            #pragma unroll
            for (int p = 0; p < 4; ++p) {
                const int cbase = p * 16 + 4 * w;
                const int c     = cbase + q;
                float4 xv = xg[((size_t)c * TT + (t0 + t)) * 16 + f4i];
                float v0 = xv.x, v1 = xv.y, v2 = xv.z, v3 = xv.w;
                // step 1: exchange across lane^16 (bit0 of q)
                float s01 = __shfl_xor((q & 1) ? v0 : v1, 16);
                float s23 = __shfl_xor((q & 1) ? v2 : v3, 16);
                float w0 = (q & 1) ? s01 : v0;
                float w1 = (q & 1) ? v1  : s01;
                float w2 = (q & 1) ? s23 : v2;
                float w3 = (q & 1) ? v3  : s23;
                // step 2: exchange across lane^32 (bit1 of q)
                float r02 = __shfl_xor((q & 2) ? w0 : w2, 32);
                float r13 = __shfl_xor((q & 2) ? w1 : w3, 32);
                float u0 = (q & 2) ? r02 : w0;
                float u1 = (q & 2) ? r13 : w1;
                float u2 = (q & 2) ? w2  : r02;
                float u3 = (q & 2) ? w3  : r13;
                // lane now holds x[cbase+0..3][f0+q], f0 = 4*f4i
                unsigned a0 = (unsigned)f2bf(u0) | ((unsigned)f2bf(u1) << 16);
                unsigned a1 = (unsigned)f2bf(u2) | ((unsigned)f2bf(u3) << 16);
                uint2* dst = reinterpret_cast<uint2*>(
                    &Xt[t][(4 * f4i + q) * 72 + cbase]);
                *dst = make_uint2(a0, a1);
            }
        }
    }
    __syncthreads();

    // ---- A-frags (W rows of this wave's m-tile), cached across t ----
    short8 a0 = *reinterpret_cast<const short8*>(&Wl[(16 * w + f4i) * 72 + q * 8]);
    short8 a1 = *reinterpret_cast<const short8*>(&Wl[(16 * w + f4i) * 72 + (4 + q) * 8]);

    #pragma unroll
    for (int t = 0; t < 2; ++t) {
        f32x4 acc[4];
        #pragma unroll
        for (int n = 0; n < 4; ++n) acc[n] = (f32x4){0.f, 0.f, 0.f, 0.f};

        #pragma unroll
        for (int n = 0; n < 4; ++n) {
            short8 b0 = *reinterpret_cast<const short8*>(
                &Xt[t][(16 * n + f4i) * 72 + q * 8]);
            short8 b1 = *reinterpret_cast<const short8*>(
                &Xt[t][(16 * n + f4i) * 72 + (4 + q) * 8]);
            acc[n] = __builtin_amdgcn_mfma_f32_16x16x32_bf16(a0, b0, acc[n], 0, 0, 0);
            acc[n] = __builtin_amdgcn_mfma_f32_16x16x32_bf16(a1, b1, acc[n], 0, 0, 0);
        }
        // store: h = 16w + 4q + r, f = 16n + f4i
        #pragma unroll
        for (int n = 0; n < 4; ++n) {
            #pragma unroll
            for (int r = 0; r < 4; ++r) {
                const int h = 16 * w + 4 * q + r;
                const int f = 16 * n + f4i;
                float val = acc[n][r] + Bs[h];
                outb[((size_t)(b * HH + h) * TT + (t0 + t)) * FF + f] = f2bf(val);
            }
        }
    }
}

// ---------------------------------------------------------------------------
// K2 (MFMA): V[b,t,h,d] = (1/8) * sum_f Qb[t,f] * Kb[t+d-31,f]
// Banded GEMM C[t][j] = Q[t]·K[j], j = t+d-31.  Block (t64, h, b); wave w
// owns t16-tile; 3 j-tiles x 2 k-tiles = 6 MFMA; store masked 0<=d<32.
// ---------------------------------------------------------------------------
__global__ __launch_bounds__(256) void k_scores(
    const unsigned short* __restrict__ Qb, const unsigned short* __restrict__ Kb,
    float* __restrict__ V)
{
    __shared__ unsigned short Ql[64 * 72];   // rows t0..t0+63
    __shared__ unsigned short Kl[96 * 72];   // rows j = t0-31 .. t0+64

    const int tid = threadIdx.x;
    const int t0  = blockIdx.x * 64;
    const int h   = blockIdx.y, b = blockIdx.z;

    const size_t base = ((size_t)(b * HH + h) * TT) * FF;

    // stage: 512 Q-granules + 768 K-granules (16B each)
    #pragma unroll
    for (int it = 0; it < 5; ++it) {
        int idx = it * 256 + tid;
        if (idx < 512) {
            int r = idx >> 3, g = idx & 7;
            uint4 v = *reinterpret_cast<const uint4*>(Qb + base + (size_t)(t0 + r) * FF + g * 8);
            *reinterpret_cast<uint4*>(&Ql[r * 72 + g * 8]) = v;
        } else {
            int idx2 = idx - 512;
            int r = idx2 >> 3, g = idx2 & 7;
            int j = t0 - 31 + r;
            uint4 v = make_uint4(0u, 0u, 0u, 0u);
            if (j >= 0 && j < TT)
                v = *reinterpret_cast<const uint4*>(Kb + base + (size_t)j * FF + g * 8);
            *reinterpret_cast<uint4*>(&Kl[r * 72 + g * 8]) = v;
        }
    }
    __syncthreads();

    const int l = tid & 63;
    const int w = tid >> 6;
    const int q = l >> 4;
    const int nl = l & 15;

    short8 a0 = *reinterpret_cast<const short8*>(&Ql[(16 * w + nl) * 72 + q * 8]);
    short8 a1 = *reinterpret_cast<const short8*>(&Ql[(16 * w + nl) * 72 + (4 + q) * 8]);

    f32x4 acc[3];
    #pragma unroll
    for (int n = 0; n < 3; ++n) acc[n] = (f32x4){0.f, 0.f, 0.f, 0.f};

    #pragma unroll
    for (int n = 0; n < 3; ++n) {
        short8 b0 = *reinterpret_cast<const short8*>(
            &Kl[(16 * w + 16 * n + nl) * 72 + q * 8]);
        short8 b1 = *reinterpret_cast<const short8*>(
            &Kl[(16 * w + 16 * n + nl) * 72 + (4 + q) * 8]);
        acc[n] = __builtin_amdgcn_mfma_f32_16x16x32_bf16(a0, b0, acc[n], 0, 0, 0);
        acc[n] = __builtin_amdgcn_mfma_f32_16x16x32_bf16(a1, b1, acc[n], 0, 0, 0);
    }

    #pragma unroll
    for (int n = 0; n < 3; ++n) {
        #pragma unroll
        for (int r = 0; r < 4; ++r) {
            const int tloc = 16 * w + 4 * q + r;
            const int d = 16 * n + nl - 4 * q - r;
            if (d >= 0 && d < DD) {
                const int t = t0 + tloc;
                V[((size_t)(b * TT + t) * HH + h) * DD + d] = acc[n][r] * 0.125f;
            }
        }
    }
}

// ---------------------------------------------------------------------------
// K3: conv (5,3) over (t,d) reducing H -> softmax over d.  (unchanged)
// ---------------------------------------------------------------------------
__global__ __launch_bounds__(256) void k_conv_softmax(
    const float* __restrict__ V, const float* __restrict__ wconv,
    const float* __restrict__ bconv, float* __restrict__ A)
{
    __shared__ float Vs[4 + 5 * 2048 + 4];
    __shared__ float wcs[960];
    __shared__ float parts[8 * 32];

    const int tid = threadIdx.x;
    const int t = blockIdx.x, b = blockIdx.y;

    #pragma unroll
    for (int idx = tid; idx < 960; idx += 256) wcs[idx] = wconv[idx];

    const float4* vg = reinterpret_cast<const float4*>(V);
    float4* vs4 = reinterpret_cast<float4*>(Vs);
    #pragma unroll
    for (int idx = tid; idx < 5 * 512; idx += 256) {
        int i = idx >> 9, f4i = idx & 511;
        int tt = t - 4 + i;
        float4 v = make_float4(0.f, 0.f, 0.f, 0.f);
        if (tt >= 0) v = vg[((size_t)(b * TT) + tt) * 512 + f4i];
        vs4[1 + idx] = v;
    }
    __syncthreads();

    const int d  = tid & 31;
    const int hg = tid >> 5;
    float s = 0.f;
    #pragma unroll
    for (int i = 0; i < 5; ++i) {
        #pragma unroll
        for (int hh = 0; hh < 8; ++hh) {
            int h = hg * 8 + hh;
            int base = 4 + i * 2048 + h * 32 + d;
            float vm = Vs[base - 1];  vm = (d > 0)  ? vm : 0.f;
            float v0 = Vs[base];
            float vp = Vs[base + 1];  vp = (d < 31) ? vp : 0.f;
            const float* wr = &wcs[h * 15 + i * 3];
            s += vm * wr[0] + v0 * wr[1] + vp * wr[2];
        }
    }
    parts[hg * 32 + d] = s;
    __syncthreads();

    if (tid < 32) {
        float vc = bconv[0];
        #pragma unroll
        for (int g = 0; g < 8; ++g) vc += parts[g * 32 + tid];
        float m = vc;
        #pragma unroll
        for (int off = 16; off >= 1; off >>= 1) m = fmaxf(m, __shfl_xor(m, off));
        float e = __expf(vc - m);
        float ssum = e;
        #pragma unroll
        for (int off = 16; off >= 1; off >>= 1) ssum += __shfl_xor(ssum, off);
        A[((size_t)(b * TT) + t) * DD + tid] = e / ssum;
    }
}

// ---------------------------------------------------------------------------
// K4: aligned[b,c,t,f] = sum_d A[b,t,d] * x_ref[b,c,t+d-31,f]  (unchanged)
// ---------------------------------------------------------------------------
__global__ __launch_bounds__(256) void k_align(
    const float* __restrict__ x_ref, const float* __restrict__ A, float* __restrict__ out)
{
    __shared__ float Xs[63 * 68];
    __shared__ float As[32 * 33];

    const int tid = threadIdx.x;
    const int t0  = blockIdx.x * 32;
    const int c   = blockIdx.y, b = blockIdx.z;

    const float4* xg = reinterpret_cast<const float4*>(
        x_ref + ((size_t)(b * CC + c) * TT) * FF);
    float4* xs4 = reinterpret_cast<float4*>(Xs);
    #pragma unroll
    for (int idx = tid; idx < 63 * 16; idx += 256) {
        int r = idx >> 4, f4 = idx & 15;
        int tt = t0 - 31 + r;
        float4 v = make_float4(0.f, 0.f, 0.f, 0.f);
        if (tt >= 0) v = xg[tt * 16 + f4];
        xs4[r * 17 + f4] = v;
    }
    #pragma unroll
    for (int idx = tid; idx < 32 * 32; idx += 256) {
        int i = idx >> 5, d = idx & 31;
        As[i * 33 + d] = A[((size_t)(b * TT) + t0 + i) * DD + d];
    }
    __syncthreads();

    const int f4 = tid & 15;
    const int i0 = tid >> 4;
    float4* out4 = reinterpret_cast<float4*>(out);

    #pragma unroll
    for (int pass = 0; pass < 2; ++pass) {
        const int i = i0 + pass * 16;
        float ax = 0.f, ay = 0.f, az = 0.f, aw = 0.f;
        #pragma unroll 8
        for (int d = 0; d < 32; ++d) {
            float a = As[i * 33 + d];
            float4 x = xs4[(i + d) * 17 + f4];
            ax += a * x.x; ay += a * x.y; az += a * x.z; aw += a * x.w;
        }
        out4[((size_t)(b * CC + c) * TT + t0 + i) * 16 + f4] =
            make_float4(ax, ay, az, aw);
    }
}

// ---------------------------------------------------------------------------
extern "C" void kernel_launch(void* const* d_in, const int* in_sizes, int n_in,
                              void* d_out, int out_size, void* d_ws, size_t ws_size,
                              hipStream_t stream)
{
    const float* x_mic  = (const float*)d_in[0];
    const float* x_ref  = (const float*)d_in[1];
    const float* w_mic  = (const float*)d_in[2];
    const float* b_mic  = (const float*)d_in[3];
    const float* w_ref  = (const float*)d_in[4];
    const float* b_ref  = (const float*)d_in[5];
    const float* w_conv = (const float*)d_in[6];
    const float* b_conv = (const float*)d_in[7];
    float* out = (float*)d_out;

    unsigned short* Qb = (unsigned short*)d_ws;          // B*H*T*F bf16
    unsigned short* Kb = Qb + 4194304;                   // B*H*T*F bf16
    float* V = (float*)(Kb + 4194304);                   // B*T*H*D fp32
    float* A = V + 2097152;                              // B*T*D fp32

    k_qk<<<dim3(BB * (TT / 2), 2), 256, 0, stream>>>(
        x_mic, x_ref, w_mic, b_mic, w_ref, b_ref, Qb, Kb);
    k_scores<<<dim3(TT / 64, HH, BB), 256, 0, stream>>>(Qb, Kb, V);
    k_conv_softmax<<<dim3(TT, BB), 256, 0, stream>>>(V, w_conv, b_conv, A);
    k_align<<<dim3(TT / 32, CC, BB), 256, 0, stream>>>(x_ref, A, out);
}

// Round 5
// 124.816 us; speedup vs baseline: 1.4793x; 1.0558x over previous
//
#include <hip/hip_runtime.h>
#include <hip/hip_bf16.h>

#define BB 2
#define CC 64
#define HH 64
#define TT 512
#define FF 64
#define DD 32

typedef short short8 __attribute__((ext_vector_type(8)));
typedef float f32x4  __attribute__((ext_vector_type(4)));

__device__ __forceinline__ unsigned short f2bf(float x) {
    union { float f; unsigned u; } v; v.f = x;
    unsigned r = v.u + 0x7FFFu + ((v.u >> 16) & 1u);   // RNE
    return (unsigned short)(r >> 16);
}

// ---------------------------------------------------------------------------
// K1 (MFMA): Qb = bf16(w_mic @ x_mic + b_mic); Kb likewise.
// Operand order: A = xT (m=f), B = W (n=h)  ->  lane holds 4 CONSECUTIVE f
// (row = 4q+reg) for one h (col = lane&15): epilogue is 8 uint2 stores
// instead of 32 scalar bf16 stores.
// ---------------------------------------------------------------------------
__global__ __launch_bounds__(256) void k_qk(
    const float* __restrict__ x_mic, const float* __restrict__ x_ref,
    const float* __restrict__ w_mic, const float* __restrict__ b_mic,
    const float* __restrict__ w_ref, const float* __restrict__ b_ref,
    unsigned short* __restrict__ Qb, unsigned short* __restrict__ Kb)
{
    __shared__ unsigned short Wl[64 * 72];       // [h][c] pitch 72
    __shared__ unsigned short Xt[2][64 * 72];    // [t][f][c] pitch 72
    __shared__ float Bs[64];

    const int tid = threadIdx.x;
    const int b   = blockIdx.x >> 8;
    const int t0  = (blockIdx.x & 255) * 2;
    const int which = blockIdx.y;

    const float* xsrc = which ? x_ref : x_mic;
    const float* wsrc = which ? w_ref : w_mic;
    const float* bsrc = which ? b_ref : b_mic;
    unsigned short* outb = which ? Kb : Qb;

    const int l  = tid & 63;
    const int w  = tid >> 6;
    const int q  = l >> 4;        // quad index 0..3
    const int nl = l & 15;

    // ---- stage W as bf16 [h][c] pitch 72 ----
    {
        const float4* wg = reinterpret_cast<const float4*>(wsrc);
        const int h  = tid >> 2;
        #pragma unroll
        for (int p = 0; p < 4; ++p) {
            const int c0 = (tid & 3) * 4 + p * 16;
            float4 wv = wg[h * 16 + (c0 >> 2)];
            unsigned w0 = (unsigned)f2bf(wv.x) | ((unsigned)f2bf(wv.y) << 16);
            unsigned w1 = (unsigned)f2bf(wv.z) | ((unsigned)f2bf(wv.w) << 16);
            uint2* dst = reinterpret_cast<uint2*>(&Wl[h * 72 + c0]);
            *dst = make_uint2(w0, w1);
        }
    }
    if (tid < 64) Bs[tid] = bsrc[tid];

    // ---- stage x transposed: xT[f][c] bf16, quad-shuffle 4x4 transpose ----
    {
        const float4* xg = reinterpret_cast<const float4*>(
            xsrc + (size_t)b * CC * TT * FF);
        #pragma unroll
        for (int t = 0; t < 2; ++t) {
            #pragma unroll
            for (int p = 0; p < 4; ++p) {
                const int cbase = p * 16 + 4 * w;
                const int c     = cbase + q;
                float4 xv = xg[((size_t)c * TT + (t0 + t)) * 16 + nl];
                float v0 = xv.x, v1 = xv.y, v2 = xv.z, v3 = xv.w;
                float s01 = __shfl_xor((q & 1) ? v0 : v1, 16);
                float s23 = __shfl_xor((q & 1) ? v2 : v3, 16);
                float w0 = (q & 1) ? s01 : v0;
                float w1 = (q & 1) ? v1  : s01;
                float w2 = (q & 1) ? s23 : v2;
                float w3 = (q & 1) ? v3  : s23;
                float r02 = __shfl_xor((q & 2) ? w0 : w2, 32);
                float r13 = __shfl_xor((q & 2) ? w1 : w3, 32);
                float u0 = (q & 2) ? r02 : w0;
                float u1 = (q & 2) ? r13 : w1;
                float u2 = (q & 2) ? w2  : r02;
                float u3 = (q & 2) ? w3  : r13;
                unsigned a0 = (unsigned)f2bf(u0) | ((unsigned)f2bf(u1) << 16);
                unsigned a1 = (unsigned)f2bf(u2) | ((unsigned)f2bf(u3) << 16);
                uint2* dst = reinterpret_cast<uint2*>(
                    &Xt[t][(4 * nl + q) * 72 + cbase]);
                *dst = make_uint2(a0, a1);
            }
        }
    }
    __syncthreads();

    // B-frags: W rows h = 16w + nl (cached for both t)
    short8 b0 = *reinterpret_cast<const short8*>(&Wl[(16 * w + nl) * 72 + q * 8]);
    short8 b1 = *reinterpret_cast<const short8*>(&Wl[(16 * w + nl) * 72 + (4 + q) * 8]);
    const int h = 16 * w + nl;
    const float bv = Bs[h];

    #pragma unroll
    for (int t = 0; t < 2; ++t) {
        #pragma unroll
        for (int mt = 0; mt < 4; ++mt) {
            f32x4 acc = (f32x4){0.f, 0.f, 0.f, 0.f};
            short8 a0 = *reinterpret_cast<const short8*>(
                &Xt[t][(16 * mt + nl) * 72 + q * 8]);
            short8 a1 = *reinterpret_cast<const short8*>(
                &Xt[t][(16 * mt + nl) * 72 + (4 + q) * 8]);
            acc = __builtin_amdgcn_mfma_f32_16x16x32_bf16(a0, b0, acc, 0, 0, 0);
            acc = __builtin_amdgcn_mfma_f32_16x16x32_bf16(a1, b1, acc, 0, 0, 0);
            // lane: f = 16mt + 4q + r, h = 16w + nl
            unsigned lo = (unsigned)f2bf(acc[0] + bv) | ((unsigned)f2bf(acc[1] + bv) << 16);
            unsigned hi = (unsigned)f2bf(acc[2] + bv) | ((unsigned)f2bf(acc[3] + bv) << 16);
            uint2* dst = reinterpret_cast<uint2*>(
                &outb[((size_t)(b * HH + h) * TT + (t0 + t)) * FF + 16 * mt + 4 * q]);
            *dst = make_uint2(lo, hi);
        }
    }
}

// ---------------------------------------------------------------------------
// K2 (MFMA): V[b,t,h,d] = (1/8) * sum_f Qb[t,f] * Kb[t+d-31,f]   (unchanged)
// ---------------------------------------------------------------------------
__global__ __launch_bounds__(256) void k_scores(
    const unsigned short* __restrict__ Qb, const unsigned short* __restrict__ Kb,
    float* __restrict__ V)
{
    __shared__ unsigned short Ql[64 * 72];
    __shared__ unsigned short Kl[96 * 72];

    const int tid = threadIdx.x;
    const int t0  = blockIdx.x * 64;
    const int h   = blockIdx.y, b = blockIdx.z;

    const size_t base = ((size_t)(b * HH + h) * TT) * FF;

    #pragma unroll
    for (int it = 0; it < 5; ++it) {
        int idx = it * 256 + tid;
        if (idx < 512) {
            int r = idx >> 3, g = idx & 7;
            uint4 v = *reinterpret_cast<const uint4*>(Qb + base + (size_t)(t0 + r) * FF + g * 8);
            *reinterpret_cast<uint4*>(&Ql[r * 72 + g * 8]) = v;
        } else {
            int idx2 = idx - 512;
            int r = idx2 >> 3, g = idx2 & 7;
            int j = t0 - 31 + r;
            uint4 v = make_uint4(0u, 0u, 0u, 0u);
            if (j >= 0 && j < TT)
                v = *reinterpret_cast<const uint4*>(Kb + base + (size_t)j * FF + g * 8);
            *reinterpret_cast<uint4*>(&Kl[r * 72 + g * 8]) = v;
        }
    }
    __syncthreads();

    const int l = tid & 63;
    const int w = tid >> 6;
    const int q = l >> 4;
    const int nl = l & 15;

    short8 a0 = *reinterpret_cast<const short8*>(&Ql[(16 * w + nl) * 72 + q * 8]);
    short8 a1 = *reinterpret_cast<const short8*>(&Ql[(16 * w + nl) * 72 + (4 + q) * 8]);

    f32x4 acc[3];
    #pragma unroll
    for (int n = 0; n < 3; ++n) acc[n] = (f32x4){0.f, 0.f, 0.f, 0.f};

    #pragma unroll
    for (int n = 0; n < 3; ++n) {
        short8 b0 = *reinterpret_cast<const short8*>(
            &Kl[(16 * w + 16 * n + nl) * 72 + q * 8]);
        short8 b1 = *reinterpret_cast<const short8*>(
            &Kl[(16 * w + 16 * n + nl) * 72 + (4 + q) * 8]);
        acc[n] = __builtin_amdgcn_mfma_f32_16x16x32_bf16(a0, b0, acc[n], 0, 0, 0);
        acc[n] = __builtin_amdgcn_mfma_f32_16x16x32_bf16(a1, b1, acc[n], 0, 0, 0);
    }

    #pragma unroll
    for (int n = 0; n < 3; ++n) {
        #pragma unroll
        for (int r = 0; r < 4; ++r) {
            const int tloc = 16 * w + 4 * q + r;
            const int d = 16 * n + nl - 4 * q - r;
            if (d >= 0 && d < DD) {
                const int t = t0 + tloc;
                V[((size_t)(b * TT + t) * HH + h) * DD + d] = acc[n][r] * 0.125f;
            }
        }
    }
}

// ---------------------------------------------------------------------------
// K3: conv (5,3) over (t,d) reducing H -> softmax over d.
// Block = 4 t (grid 128x2), 256 thr. Thread = (dq = tid&7: d-quad,
// hg = (tid>>3)&7: h-partial, wave = one t). 1 b128 per (i,h); d+-1 via
// shfl; hg-reduce + softmax fully via shfl_xor (no LDS roundtrip).
// V rows staged [row][h][36] (pitch-36 per h).
// ---------------------------------------------------------------------------
__global__ __launch_bounds__(256) void k_conv_softmax(
    const float* __restrict__ V, const float* __restrict__ wconv,
    const float* __restrict__ bconv, float* __restrict__ A)
{
    __shared__ float Vs[8 * 2304];      // [row][h][36]
    __shared__ float wcs[960];          // [h][i][j]

    const int tid = threadIdx.x;
    const int t0 = blockIdx.x * 4, b = blockIdx.y;

    #pragma unroll
    for (int idx = tid; idx < 960; idx += 256) wcs[idx] = wconv[idx];

    const float4* vg = reinterpret_cast<const float4*>(V);
    #pragma unroll
    for (int it = 0; it < 16; ++it) {
        int idx = it * 256 + tid;          // [0, 4096)
        int r = idx >> 9, g = idx & 511;   // row, f4-granule
        int h = g >> 3, d4 = g & 7;
        int tt = t0 - 4 + r;
        float4 v = make_float4(0.f, 0.f, 0.f, 0.f);
        if (tt >= 0) v = vg[((size_t)(b * TT) + tt) * 512 + g];
        *reinterpret_cast<float4*>(&Vs[r * 2304 + h * 36 + d4 * 4]) = v;
    }
    __syncthreads();

    const int dq = tid & 7;
    const int hg = (tid >> 3) & 7;
    const int tt = tid >> 6;              // wave id = local t

    float px = 0.f, py = 0.f, pz = 0.f, pw = 0.f;
    #pragma unroll
    for (int i = 0; i < 5; ++i) {
        const int r = tt + i;             // staged row
        #pragma unroll
        for (int hh = 0; hh < 8; ++hh) {
            const int h = hg + 8 * hh;
            float4 cur = *reinterpret_cast<const float4*>(
                &Vs[r * 2304 + h * 36 + dq * 4]);
            float pv = __shfl_up(cur.w, 1);
            float nx = __shfl_down(cur.x, 1);
            if (dq == 0) pv = 0.f;
            if (dq == 7) nx = 0.f;
            const float w0 = wcs[h * 15 + i * 3 + 0];
            const float w1 = wcs[h * 15 + i * 3 + 1];
            const float w2 = wcs[h * 15 + i * 3 + 2];
            px += w0 * pv    + w1 * cur.x + w2 * cur.y;
            py += w0 * cur.x + w1 * cur.y + w2 * cur.z;
            pz += w0 * cur.y + w1 * cur.z + w2 * cur.w;
            pw += w0 * cur.z + w1 * cur.w + w2 * nx;
        }
    }
    // reduce over hg (lane bits 3,4,5)
    #pragma unroll
    for (int off = 8; off <= 32; off <<= 1) {
        px += __shfl_xor(px, off);
        py += __shfl_xor(py, off);
        pz += __shfl_xor(pz, off);
        pw += __shfl_xor(pw, off);
    }
    const float bc = bconv[0];
    px += bc; py += bc; pz += bc; pw += bc;
    // softmax over the 32 d (4 per lane x 8 dq); replicated over hg
    float m = fmaxf(fmaxf(px, py), fmaxf(pz, pw));
    #pragma unroll
    for (int off = 1; off <= 4; off <<= 1) m = fmaxf(m, __shfl_xor(m, off));
    float ex = __expf(px - m), ey = __expf(py - m);
    float ez = __expf(pz - m), ew = __expf(pw - m);
    float s = ex + ey + ez + ew;
    #pragma unroll
    for (int off = 1; off <= 4; off <<= 1) s += __shfl_xor(s, off);
    const float inv = 1.f / s;
    if (hg == 0) {
        const int t = t0 + tt;
        float4 av = make_float4(ex * inv, ey * inv, ez * inv, ew * inv);
        *reinterpret_cast<float4*>(&A[((size_t)(b * TT) + t) * DD + 4 * dq]) = av;
    }
}

// ---------------------------------------------------------------------------
// K4: aligned[b,c,t,f] = sum_d A[b,t,d] * x_ref[b,c,t+d-31,f]
// Block = (t-tile 64, c, b), 256 thr: f4 = tid&15, bi = tid>>4 (4 out rows).
// Band weights pre-packed: Ap[bi][rr] = float4 of A[4bi+r][rr-r] (zeros
// outside) -> inner loop = 1 X-b128 + 1 Ap-b128-broadcast per rr for 16 FMA.
// ---------------------------------------------------------------------------
__global__ __launch_bounds__(256) void k_align(
    const float* __restrict__ x_ref, const float* __restrict__ A, float* __restrict__ out)
{
    __shared__ float Xs[95 * 68];       // [row][f] pad 68
    __shared__ float As[64 * 36];       // [i][d] staging
    __shared__ float Ap[16 * 37 * 4];   // packed float4 [bi][rr], pitch 37

    const int tid = threadIdx.x;
    const int t0  = blockIdx.x * 64;
    const int c   = blockIdx.y, b = blockIdx.z;

    const float4* xg = reinterpret_cast<const float4*>(
        x_ref + ((size_t)(b * CC + c) * TT) * FF);
    float4* xs4 = reinterpret_cast<float4*>(Xs);
    #pragma unroll
    for (int it = 0; it < 6; ++it) {
        int idx = it * 256 + tid;
        if (idx < 95 * 16) {
            int r = idx >> 4, f4 = idx & 15;
            int tt = t0 - 31 + r;
            float4 v = make_float4(0.f, 0.f, 0.f, 0.f);
            if (tt >= 0) v = xg[tt * 16 + f4];
            xs4[r * 17 + f4] = v;
        }
    }
    #pragma unroll
    for (int it = 0; it < 2; ++it) {
        int idx = it * 256 + tid;          // 512 granules = 64 rows x 8
        int i = idx >> 3, d4 = idx & 7;
        *reinterpret_cast<float4*>(&As[i * 36 + 4 * d4]) =
            *reinterpret_cast<const float4*>(&A[((size_t)(b * TT) + t0 + i) * DD + 4 * d4]);
    }
    __syncthreads();
    #pragma unroll
    for (int it = 0; it < 3; ++it) {
        int idx = it * 256 + tid;
        if (idx < 16 * 37) {
            int bi = idx / 37, rr = idx - bi * 37;
            float wv[4];
            #pragma unroll
            for (int r = 0; r < 4; ++r) {
                int d = rr - r;
                wv[r] = (d >= 0 && d < 32) ? As[(4 * bi + r) * 36 + d] : 0.f;
            }
            float4* dst = reinterpret_cast<float4*>(&Ap[(bi * 37 + rr) * 4]);
            *dst = make_float4(wv[0], wv[1], wv[2], wv[3]);
        }
    }
    __syncthreads();

    const int f4 = tid & 15;
    const int bi = tid >> 4;

    float4 acc0 = make_float4(0.f, 0.f, 0.f, 0.f);
    float4 acc1 = make_float4(0.f, 0.f, 0.f, 0.f);
    float4 acc2 = make_float4(0.f, 0.f, 0.f, 0.f);
    float4 acc3 = make_float4(0.f, 0.f, 0.f, 0.f);

    #pragma unroll 7
    for (int rr = 0; rr < 35; ++rr) {
        float4 W4 = *reinterpret_cast<const float4*>(&Ap[(bi * 37 + rr) * 4]);
        float4 X4 = xs4[(4 * bi + rr) * 17 + f4];
        acc0.x += W4.x * X4.x; acc0.y += W4.x * X4.y; acc0.z += W4.x * X4.z; acc0.w += W4.x * X4.w;
        acc1.x += W4.y * X4.x; acc1.y += W4.y * X4.y; acc1.z += W4.y * X4.z; acc1.w += W4.y * X4.w;
        acc2.x += W4.z * X4.x; acc2.y += W4.z * X4.y; acc2.z += W4.z * X4.z; acc2.w += W4.z * X4.w;
        acc3.x += W4.w * X4.x; acc3.y += W4.w * X4.y; acc3.z += W4.w * X4.z; acc3.w += W4.w * X4.w;
    }

    float4* o4 = reinterpret_cast<float4*>(out);
    const size_t obase = ((size_t)(b * CC + c) * TT + t0 + 4 * bi) * 16 + f4;
    o4[obase +  0] = acc0;
    o4[obase + 16] = acc1;
    o4[obase + 32] = acc2;
    o4[obase + 48] = acc3;
}

// ---------------------------------------------------------------------------
extern "C" void kernel_launch(void* const* d_in, const int* in_sizes, int n_in,
                              void* d_out, int out_size, void* d_ws, size_t ws_size,
                              hipStream_t stream)
{
    const float* x_mic  = (const float*)d_in[0];
    const float* x_ref  = (const float*)d_in[1];
    const float* w_mic  = (const float*)d_in[2];
    const float* b_mic  = (const float*)d_in[3];
    const float* w_ref  = (const float*)d_in[4];
    const float* b_ref  = (const float*)d_in[5];
    const float* w_conv = (const float*)d_in[6];
    const float* b_conv = (const float*)d_in[7];
    float* out = (float*)d_out;

    unsigned short* Qb = (unsigned short*)d_ws;          // B*H*T*F bf16
    unsigned short* Kb = Qb + 4194304;                   // B*H*T*F bf16
    float* V = (float*)(Kb + 4194304);                   // B*T*H*D fp32
    float* A = V + 2097152;                              // B*T*D fp32

    k_qk<<<dim3(BB * (TT / 2), 2), 256, 0, stream>>>(
        x_mic, x_ref, w_mic, b_mic, w_ref, b_ref, Qb, Kb);
    k_scores<<<dim3(TT / 64, HH, BB), 256, 0, stream>>>(Qb, Kb, V);
    k_conv_softmax<<<dim3(TT / 4, BB), 256, 0, stream>>>(V, w_conv, b_conv, A);
    k_align<<<dim3(TT / 64, CC, BB), 256, 0, stream>>>(x_ref, A, out);
}